// Round 11
// baseline (265.263 us; speedup 1.0000x reference)
//
#include <hip/hip_runtime.h>

// MHA: B=2, S=2048, D=1024, H=16, DK=64. I/O bf16 (harness-confirmed R4);
// dual fp32 path retained via runtime inline detect. mask int32.
//
// Pipeline (ws 16 MB; d_out doubles as V scratch) -- 3 dispatches:
//   1) gemmqkv: Q/K/V proj, 256x256 tile, BK=32, depth-4 counted-vmcnt
//      pipeline (one launch, z selects tensor). z=0: Qh scaled; z=1: Kh;
//      z=2: Vt [B,H,DK,S] transposed.
//   2) attn (R18 form, byte-identical): flash, 128 q-rows/block.
//   3) gemmk<64,128,1>: out = ctx @ Wo^T -> d_out (R19-verbatim).
//
// MFMA 16x16x32 bf16 layouts (verified):
//   A: lane holds A[m=lane&15][k=(lane>>4)*8+j]
//   B: lane holds B[k=(lane>>4)*8+j][n=lane&15]
//   C/D: col=lane&15, row=(lane>>4)*4+reg
//
// R4: no u16/bf16 punning (TBAA reorder -> NaN).
// R9/R16: BK=64-style chunk-XOR swizzles proven 0-conflict; BK=128's
//   16-chunk XOR aliases banks.
// R10 FAILED: ds_read_b64_tr_b16 gather model wrong.
// R11: swapped-MFMA packed-P attn 85.6 -> 75.6 us.
// R12-R17: gemm schedule ladder all flat-to-worse at 77-90 us. Lessons:
//   drain-to-0 at barriers is the stall (R12/R13); counted vmcnt must not
//   cost occupancy it needs (R15); conflicts kill BK=128 (R16).
// R18: attn XCD-swizzle + setprio = big win; gemm XCD-swizzle backfired
//   (A-panel L2 thrash, FETCH 3x) -> reverted R19 (248.9, best).
// R20 (this round): QKV -> m201-class geometry where the PIPELINE
//   replaces TLP: 512-thr block (8 waves, 2x4 grid, 128x64 out each),
//   4 rotating 32KB tile-buffers (128KB LDS, 1 block/CU, 192 blocks),
//   BK=32, 32 K-steps. Per step: 12 ds_read_b128 -> stage tile kt+3
//   (4 gload_lds) -> vmcnt(8) [forces kt+1 ONLY; 8 loads stay in flight,
//   never drains] -> fenced barrier -> lgkm0+sched_barrier (rule #18) ->
//   32 MFMA -> fenced barrier. Safety: per-wave vmcnt + following barrier
//   composes to a global guarantee; buf (kt+3)%4=(kt-1)%4 last read two
//   barriers earlier; 4-chunk XOR hand-verified bank-balanced (8/bank =
//   floor). No setprio (lockstep block = m190 null regime).
//   attn + out-proj byte-identical to R19.

typedef __bf16 bf16x8 __attribute__((ext_vector_type(8)));
typedef __bf16 bf16x4 __attribute__((ext_vector_type(4)));
typedef float f32x4 __attribute__((ext_vector_type(4)));

#define B_ 2
#define S_ 2048
#define D_ 1024
#define H_ 16
#define DK_ 64
#define QSCALE 0.18033688011112042f  // 0.125 * log2(e)

// fenced barrier: real s_barrier + compiler memory fence both sides
__device__ __forceinline__ void barrier_fenced() {
  asm volatile("s_barrier" ::: "memory");
}

template <int N>
__device__ __forceinline__ void wait_vmcnt() {
  if constexpr (N == 0) asm volatile("s_waitcnt vmcnt(0)" ::: "memory");
  else if constexpr (N == 4) asm volatile("s_waitcnt vmcnt(4)" ::: "memory");
  else if constexpr (N == 8) asm volatile("s_waitcnt vmcnt(8)" ::: "memory");
  else static_assert(N == 0 || N == 4 || N == 8, "unsupported vmcnt");
  __builtin_amdgcn_sched_barrier(0);  // rule #18: pin motion at the wait
}

// ---------------------------------------------------------------------------
// per-wave inline dtype detect: classify first 256 words of q. bf16 pairs
// put a real exponent at bits [14:7]; f32 words put mantissa there.
__device__ __forceinline__ bool detect_f32_wave(const unsigned* qw, int lane) {
  int cnt = 0;
#pragma unroll
  for (int i = 0; i < 4; ++i) {
    unsigned w = qw[lane + 64 * i];
    int e = (w >> 7) & 0xFF;
    cnt += (e >= 100 && e <= 140) ? 1 : 0;
  }
#pragma unroll
  for (int off = 32; off > 0; off >>= 1) cnt += __shfl_down(cnt, off, 64);
  return __shfl(cnt, 0, 64) < 128;
}

__device__ __forceinline__ bf16x8 load8cvt(const void* base, size_t eoff,
                                           bool f32) {
  if (!f32) return *(const bf16x8*)((const __bf16*)base + eoff);
  const float* p = (const float*)base + eoff;
  bf16x8 r;
#pragma unroll
  for (int j = 0; j < 8; ++j) r[j] = (__bf16)p[j];
  return r;
}

// async 16B global -> LDS (lds dest = wave-uniform base + lane*16)
__device__ __forceinline__ void async_cp16(const __bf16* g, __bf16* l) {
  __builtin_amdgcn_global_load_lds(
      (const __attribute__((address_space(1))) unsigned int*)g,
      (__attribute__((address_space(3))) unsigned int*)l, 16, 0, 0);
}

// ---------------------------------------------------------------------------
// QKV GEMM (R20): C[4096,1024] = X @ W^T per z-slice. 256x256 block tile,
// BK=32, 512 threads (8 waves, 2x4; wave out 128x64: MI=8, NI=4).
// LDS: 4 rotating buffers of (A 256x32 + B 256x32) = 4 x 32KB = 128KB.
// Tile kt lives in buf kt%4. Step kt: frag-read buf kt%4; stage kt+3 into
// buf (kt+3)%4; vmcnt(8) forces kt+1 (8 loads of kt+2/kt+3 remain in
// flight); barrier; lgkm0; 32 MFMA; barrier.
// Swizzle: 4 chunks/row, phys chunk = logical ^ (row&3); staging uses
// linear LDS dest + pre-swizzled global source (rule #21); fragment reads
// land 8 accesses/bank (minimum) -- conflict-free by construction.
// f32 fallback: single-buffer 2-barrier loop, reg-staged converts.
// ---------------------------------------------------------------------------
__global__ __launch_bounds__(512, 2) void gemmqkv(
    const void* X0, const void* X1, const void* X2,
    const void* W0, const void* W1, const void* W2,
    void* O0, void* O1, void* O2, const unsigned* __restrict__ qdet) {
  __shared__ __attribute__((aligned(16))) __bf16 As4[4][8192];  // [buf][256*32]
  __shared__ __attribute__((aligned(16))) __bf16 Bs4[4][8192];

  const void* X = (blockIdx.z == 0) ? X0 : (blockIdx.z == 1 ? X1 : X2);
  const void* W = (blockIdx.z == 0) ? W0 : (blockIdx.z == 1 ? W1 : W2);
  void* O = (blockIdx.z == 0) ? O0 : (blockIdx.z == 1 ? O1 : O2);

  const int t = threadIdx.x;
  const int lane = t & 63, wave = t >> 6;
  const int l15 = lane & 15, quad = lane >> 4;
  const int m0 = blockIdx.x * 256;
  const int n0 = blockIdx.y * 256;
  const int wm = (wave >> 2) * 128;   // wave rows [wm, wm+128)
  const int wn = (wave & 3) * 64;    // wave cols [wn, wn+64)

  const bool f32io = detect_f32_wave(qdet, lane);

  // staging precompute: thread's 2 chunks per tile per operand.
  // chunk p = j*512 + wave*64 + lane in [0,1024); row = p>>2;
  // logical chunk jl = (p&3) ^ (row&3); LDS dest = chunk p (linear).
  int srow[2], scol[2], sdst[2];
#pragma unroll
  for (int j = 0; j < 2; ++j) {
    int p = j * 512 + wave * 64 + lane;
    srow[j] = p >> 2;
    scol[j] = (((p & 3) ^ (srow[j] & 3)) << 3);
    sdst[j] = (j * 512 + wave * 64) << 3;   // elem offset of wave's chunk base
  }

  f32x4 acc[8][4] = {};

  if (!f32io) {
    auto stageT = [&](int kt, int bb) {
#pragma unroll
      for (int j = 0; j < 2; ++j)
        async_cp16((const __bf16*)X + (size_t)(m0 + srow[j]) * 1024 + kt * 32 +
                       scol[j],
                   &As4[bb][sdst[j]]);
#pragma unroll
      for (int j = 0; j < 2; ++j)
        async_cp16((const __bf16*)W + (size_t)(n0 + srow[j]) * 1024 + kt * 32 +
                       scol[j],
                   &Bs4[bb][sdst[j]]);
    };

    // prologue: tiles 0,1,2 in flight; force tile 0; sync.
    stageT(0, 0);
    stageT(1, 1);
    stageT(2, 2);
    wait_vmcnt<8>();
    barrier_fenced();

    int bb = 0;
    for (int kt = 0; kt < 32; ++kt) {
      const __bf16* Ab = &As4[bb][0];
      const __bf16* Bb = &Bs4[bb][0];
      bf16x8 af[8], bf[4];
#pragma unroll
      for (int mi = 0; mi < 8; ++mi) {
        int r = wm + mi * 16 + l15;
        af[mi] = *(const bf16x8*)&Ab[r * 32 + ((quad ^ (r & 3)) << 3)];
      }
#pragma unroll
      for (int ni = 0; ni < 4; ++ni) {
        int r = wn + ni * 16 + l15;
        bf[ni] = *(const bf16x8*)&Bb[r * 32 + ((quad ^ (r & 3)) << 3)];
      }

      if (kt < 29) {
        int nb = bb + 3;
        if (nb >= 4) nb -= 4;
        stageT(kt + 3, nb);
      }
      // force tile kt+1 only; keep kt+2/kt+3 loads in flight.
      if (kt <= 28) wait_vmcnt<8>();
      else if (kt == 29) wait_vmcnt<4>();
      else if (kt == 30) wait_vmcnt<0>();
      barrier_fenced();
      asm volatile("s_waitcnt lgkmcnt(0)" ::: "memory");
      __builtin_amdgcn_sched_barrier(0);

#pragma unroll
      for (int mi = 0; mi < 8; ++mi)
#pragma unroll
        for (int ni = 0; ni < 4; ++ni)
          acc[mi][ni] = __builtin_amdgcn_mfma_f32_16x16x32_bf16(
              af[mi], bf[ni], acc[mi][ni], 0, 0, 0);

      barrier_fenced();
      bb = (bb == 3) ? 0 : bb + 1;
    }
  } else {
    // ---- f32 fallback: single buffer, 2-barrier loop (cold path) ----
    for (int kt = 0; kt < 32; ++kt) {
      __syncthreads();
#pragma unroll
      for (int j = 0; j < 2; ++j) {
        int p = j * 512 + t;
        int r = p >> 2;
        int jl = (p & 3) ^ (r & 3);
        bf16x8 xv = load8cvt(X, (size_t)(m0 + r) * 1024 + kt * 32 + jl * 8, true);
        *(bf16x8*)&As4[0][p * 8] = xv;
        bf16x8 wv = load8cvt(W, (size_t)(n0 + r) * 1024 + kt * 32 + jl * 8, true);
        *(bf16x8*)&Bs4[0][p * 8] = wv;
      }
      __syncthreads();
      bf16x8 af[8], bf[4];
#pragma unroll
      for (int mi = 0; mi < 8; ++mi) {
        int r = wm + mi * 16 + l15;
        af[mi] = *(const bf16x8*)&As4[0][r * 32 + ((quad ^ (r & 3)) << 3)];
      }
#pragma unroll
      for (int ni = 0; ni < 4; ++ni) {
        int r = wn + ni * 16 + l15;
        bf[ni] = *(const bf16x8*)&Bs4[0][r * 32 + ((quad ^ (r & 3)) << 3)];
      }
#pragma unroll
      for (int mi = 0; mi < 8; ++mi)
#pragma unroll
        for (int ni = 0; ni < 4; ++ni)
          acc[mi][ni] = __builtin_amdgcn_mfma_f32_16x16x32_bf16(
              af[mi], bf[ni], acc[mi][ni], 0, 0, 0);
    }
  }

  // ---- epilogue: z-dependent output layouts ----
  const float oscale = (blockIdx.z == 0) ? QSCALE : 1.0f;
#pragma unroll
  for (int mi = 0; mi < 8; ++mi) {
#pragma unroll
    for (int ni = 0; ni < 4; ++ni) {
      int mbase = m0 + wm + mi * 16 + quad * 4;
      int n = n0 + wn + ni * 16 + l15;
      if (blockIdx.z == 2) {
        int b = mbase >> 11, sb = mbase & (S_ - 1);
        int h = n >> 6, dk = n & (DK_ - 1);
        bf16x4 pk;
#pragma unroll
        for (int r = 0; r < 4; ++r) pk[r] = (__bf16)acc[mi][ni][r];
        *(bf16x4*)&((__bf16*)O)[((size_t)(b * H_ + h) * DK_ + dk) * S_ + sb] = pk;
      } else {
#pragma unroll
        for (int r = 0; r < 4; ++r) {
          int m = mbase + r;
          float val = acc[mi][ni][r] * oscale;
          int b = m >> 11, s = m & (S_ - 1);
          int h = n >> 6, dk = n & (DK_ - 1);
          ((__bf16*)O)[((size_t)(b * H_ + h) * S_ + s) * DK_ + dk] = (__bf16)val;
        }
      }
    }
  }
}

// ---------------------------------------------------------------------------
// GEMM (R19-verbatim, out-proj only): C[M,N] = X[M,K] @ W[N,K]^T, TM x TN
// tile, BK=64, single LDS buffer, proven 2-barrier K-step. Natural block
// order. LDS [rows][64]; 16B chunks XOR-swizzled (phys j = jl ^ (row&7)).
// ---------------------------------------------------------------------------
template <int TM, int TN, int MODE>
__global__ __launch_bounds__(256) void gemmk(
    const void* X0, const void* X1, const void* X2,
    const void* W0, const void* W1, const void* W2,
    void* O0, void* O1, void* O2, const unsigned* __restrict__ qdet) {
  constexpr int Kd = 1024, Nd = 1024;
  constexpr int MI = TM / 32;
  constexpr int NI = TN / 32;
  constexpr int ACH = TM / 32;
  constexpr int BCH = TN / 32;
  const void* X = (blockIdx.z == 0) ? X0 : (blockIdx.z == 1 ? X1 : X2);
  const void* W = (blockIdx.z == 0) ? W0 : (blockIdx.z == 1 ? W1 : W2);
  void* O = (blockIdx.z == 0) ? O0 : (blockIdx.z == 1 ? O1 : O2);

  __shared__ __attribute__((aligned(16))) __bf16 As[TM * 64];
  __shared__ __attribute__((aligned(16))) __bf16 Bs[TN * 64];

  const int m0 = blockIdx.x * TM;
  const int n0 = blockIdx.y * TN;
  const int t = threadIdx.x;
  const int lane = t & 63, wave = t >> 6;
  const int l15 = lane & 15, quad = lane >> 4;
  const int wm = (wave >> 1) * (TM / 2);
  const int wn = (wave & 1) * (TN / 2);

  const bool f32io = detect_f32_wave(qdet, lane);

  const __bf16* gA[ACH];
  int ldsAoff[ACH];
#pragma unroll
  for (int i = 0; i < ACH; ++i) {
    int ci = (wave * ACH + i) * 64 + lane;
    int row = ci >> 3, j = ci & 7;
    int jl = j ^ (row & 7);
    ldsAoff[i] = (wave * ACH + i) * 512;
    if (MODE == 0) {
      gA[i] = (const __bf16*)X + (size_t)(m0 + row) * Kd + jl * 8;
    } else {
      int gm = m0 + row;
      gA[i] = (const __bf16*)X + (size_t)(gm >> 11) * (H_ * S_ * DK_) +
              (size_t)(gm & (S_ - 1)) * DK_ + jl * 8;
    }
  }
  const __bf16* gB[BCH];
  int ldsBoff[BCH];
#pragma unroll
  for (int i = 0; i < BCH; ++i) {
    int ci = (wave * BCH + i) * 64 + lane;
    int row = ci >> 3, j = ci & 7;
    int jl = j ^ (row & 7);
    ldsBoff[i] = (wave * BCH + i) * 512;
    gB[i] = (const __bf16*)W + (size_t)(n0 + row) * Kd + jl * 8;
  }

  f32x4 acc[MI][NI] = {};

  for (int k0 = 0; k0 < Kd; k0 += 64) {
    __syncthreads();
    if (!f32io) {
      if (MODE == 0) {
#pragma unroll
        for (int i = 0; i < ACH; ++i) async_cp16(gA[i] + k0, &As[ldsAoff[i]]);
      } else {
        const size_t koff = (size_t)(k0 >> 6) * (S_ * DK_);
#pragma unroll
        for (int i = 0; i < ACH; ++i) async_cp16(gA[i] + koff, &As[ldsAoff[i]]);
      }
#pragma unroll
      for (int i = 0; i < BCH; ++i) async_cp16(gB[i] + k0, &Bs[ldsBoff[i]]);
    } else {
#pragma unroll
      for (int i = 0; i < TM / 32; ++i) {
        int ci = t + 256 * i;
        int row = ci >> 3, j = ci & 7;
        int jl = j ^ (row & 7);
        bf16x8 xv;
        if (MODE == 0) {
          xv = load8cvt(X, (size_t)(m0 + row) * Kd + k0 + jl * 8, true);
        } else {
          int gm = m0 + row, gk = k0 + jl * 8;
          xv = *(const bf16x8*)((const __bf16*)X +
                ((((size_t)(gm >> 11) * H_ + (gk >> 6)) * S_) +
                 (gm & (S_ - 1))) * DK_ + (gk & (DK_ - 1)));
        }
        *(bf16x8*)&As[row * 64 + j * 8] = xv;
      }
#pragma unroll
      for (int i = 0; i < TN / 32; ++i) {
        int ci = t + 256 * i;
        int row = ci >> 3, j = ci & 7;
        int jl = j ^ (row & 7);
        bf16x8 wv = load8cvt(W, (size_t)(n0 + row) * Kd + k0 + jl * 8, true);
        *(bf16x8*)&Bs[row * 64 + j * 8] = wv;
      }
    }
    __syncthreads();

#pragma unroll
    for (int h = 0; h < 2; ++h) {
      bf16x8 af[MI], bfr[NI];
#pragma unroll
      for (int mi = 0; mi < MI; ++mi) {
        int row = wm + mi * 16 + l15;
        af[mi] = *(const bf16x8*)&As[row * 64 +
                                     (((h * 4 + quad) ^ (row & 7)) << 3)];
      }
#pragma unroll
      for (int ni = 0; ni < NI; ++ni) {
        int row = wn + ni * 16 + l15;
        bfr[ni] = *(const bf16x8*)&Bs[row * 64 +
                                      (((h * 4 + quad) ^ (row & 7)) << 3)];
      }
#pragma unroll
      for (int mi = 0; mi < MI; ++mi)
#pragma unroll
        for (int ni = 0; ni < NI; ++ni)
          acc[mi][ni] = __builtin_amdgcn_mfma_f32_16x16x32_bf16(
              af[mi], bfr[ni], acc[mi][ni], 0, 0, 0);
    }
  }

  const float oscale = (MODE == 0 && blockIdx.z == 0) ? QSCALE : 1.0f;
#pragma unroll
  for (int mi = 0; mi < MI; ++mi) {
#pragma unroll
    for (int ni = 0; ni < NI; ++ni) {
      int mbase = m0 + wm + mi * 16 + quad * 4;
      int n = n0 + wn + ni * 16 + l15;
      if (MODE == 0 && blockIdx.z == 2) {
        int b = mbase >> 11, sb = mbase & (S_ - 1);
        int h = n >> 6, dk = n & (DK_ - 1);
        bf16x4 pk;
#pragma unroll
        for (int r = 0; r < 4; ++r) pk[r] = (__bf16)acc[mi][ni][r];
        *(bf16x4*)&((__bf16*)O)[((size_t)(b * H_ + h) * DK_ + dk) * S_ + sb] = pk;
      } else {
#pragma unroll
        for (int r = 0; r < 4; ++r) {
          int m = mbase + r;
          float val = acc[mi][ni][r] * oscale;
          if (MODE == 0) {
            int b = m >> 11, s = m & (S_ - 1);
            int h = n >> 6, dk = n & (DK_ - 1);
            ((__bf16*)O)[((size_t)(b * H_ + h) * S_ + s) * DK_ + dk] = (__bf16)val;
          } else {
            size_t idx = (size_t)m * Nd + n;
            bool f32o = f32io;
            if (f32o) ((float*)O)[idx] = val;
            else      ((__bf16*)O)[idx] = (__bf16)val;
          }
        }
      }
    }
  }
}

// ---------------------------------------------------------------------------
// Flash attention (R18 form, byte-identical): 128 q-rows/block (32/wave
// as 2 q-tiles), 64 keys/iter, grid 512. XCD-bijective swizzle -> K/V
// L2-local. Swapped score MFMA; packed P b64/b128 round-trip; K/V frags
// shared by both q-tiles; T5 setprio around MFMA clusters.
// ---------------------------------------------------------------------------
__global__ __launch_bounds__(256, 2) void attn(
    const __bf16* Qh, const __bf16* __restrict__ Kh,
    const __bf16* __restrict__ Vt, const int* __restrict__ mask,
    __bf16* Out) {
  __shared__ __attribute__((aligned(16))) __bf16 Ks[2][4096];
  __shared__ __attribute__((aligned(16))) __bf16 Vs[2][4096];
  __shared__ __attribute__((aligned(16))) __bf16 P[4][2048];  // wave: 2 x [16][64]

  const int t = threadIdx.x;
  const int lane = t & 63, wave = t >> 6;
  const int l15 = lane & 15, quad = lane >> 4;
  // XCD-bijective remap (512 = 8 x 64)
  const int L = blockIdx.x;
  const int c = (L & 7) * 64 + (L >> 3);
  const int qb = c & 15;            // 16 q-blocks of 128
  const int bh = c >> 4;            // b*H + h
  const int b = bh >> 4;
  const int q0 = qb * 128 + wave * 32;

  const __bf16* Q = Qh + (size_t)bh * S_ * DK_;
  const __bf16* K = Kh + (size_t)bh * S_ * DK_;
  const __bf16* V = Vt + (size_t)bh * DK_ * S_;   // [dk][s]
  const int* mk = mask + b * S_;

  bf16x8 qf[2][2];
#pragma unroll
  for (int qt = 0; qt < 2; ++qt) {
    qf[qt][0] = *(const bf16x8*)&Q[(size_t)(q0 + qt * 16 + l15) * DK_ + quad * 8];
    qf[qt][1] = *(const bf16x8*)&Q[(size_t)(q0 + qt * 16 + l15) * DK_ + 32 + quad * 8];
  }

  f32x4 o[2][4] = {};
  float lsum[2] = {0.f, 0.f};

  // loop-invariant P element offsets (within P[wave], before qt*1024)
  int pst[4], prd[2];
#pragma unroll
  for (int tt = 0; tt < 4; ++tt)
    pst[tt] = l15 * 64 + (((tt * 2 + (quad >> 1)) ^ (l15 & 7)) << 3) +
              (quad & 1) * 4;
#pragma unroll
  for (int kt = 0; kt < 2; ++kt)
    prd[kt] = l15 * 64 + (((kt * 4 + quad) ^ (l15 & 7)) << 3);

  // prologue: stage tile 0 into buf 0
#pragma unroll
  for (int i = 0; i < 2; ++i) {
    int l = wave * 128 + i * 64 + lane;
    int row = l >> 3, jg = (l & 7) ^ (row & 7);
    async_cp16(K + (size_t)row * DK_ + jg * 8, &Ks[0][(size_t)(l - lane) * 8]);
    async_cp16(V + (size_t)row * S_ + jg * 8, &Vs[0][(size_t)(l - lane) * 8]);
  }
  __syncthreads();

  for (int kb = 0; kb < S_; kb += 64) {
    const int cur = (kb >> 6) & 1;
    if (kb + 64 < S_) {
#pragma unroll
      for (int i = 0; i < 2; ++i) {
        int l = wave * 128 + i * 64 + lane;
        int row = l >> 3, jg = (l & 7) ^ (row & 7);
        async_cp16(K + (size_t)(kb + 64 + row) * DK_ + jg * 8,
                   &Ks[cur ^ 1][(size_t)(l - lane) * 8]);
        async_cp16(V + (size_t)row * S_ + (kb + 64) + jg * 8,
                   &Vs[cur ^ 1][(size_t)(l - lane) * 8]);
      }
    }

    // ---- scores (SWAPPED): s[key=quad*4+r][q=l15]; K frags shared ----
    const __bf16* ks = &Ks[cur][0];
    f32x4 s[2][4];
    __builtin_amdgcn_s_setprio(1);
#pragma unroll
    for (int tt = 0; tt < 4; ++tt) {
      int row = tt * 16 + l15;
      bf16x8 kf0 = *(const bf16x8*)&ks[row * 64 + ((quad ^ (l15 & 7)) << 3)];
      bf16x8 kf1 = *(const bf16x8*)&ks[row * 64 + (((4 + quad) ^ (l15 & 7)) << 3)];
      // per-key mask bias: keys tt*16 + quad*4 .. +3
      int4 m4 = *(const int4*)&mk[kb + tt * 16 + quad * 4];
      f32x4 z;
      z[0] = m4.x ? 0.f : -1e9f;
      z[1] = m4.y ? 0.f : -1e9f;
      z[2] = m4.z ? 0.f : -1e9f;
      z[3] = m4.w ? 0.f : -1e9f;
      f32x4 z0 = __builtin_amdgcn_mfma_f32_16x16x32_bf16(kf0, qf[0][0], z, 0, 0, 0);
      s[0][tt] = __builtin_amdgcn_mfma_f32_16x16x32_bf16(kf1, qf[0][1], z0, 0, 0, 0);
      f32x4 z1 = __builtin_amdgcn_mfma_f32_16x16x32_bf16(kf0, qf[1][0], z, 0, 0, 0);
      s[1][tt] = __builtin_amdgcn_mfma_f32_16x16x32_bf16(kf1, qf[1][1], z1, 0, 0, 0);
    }
    __builtin_amdgcn_s_setprio(0);

    // ---- V fragments (issue while exp phase runs; shared by q-tiles) ----
    const __bf16* vs = &Vs[cur][0];
    bf16x8 vf[2][4];
#pragma unroll
    for (int kt = 0; kt < 2; ++kt)
#pragma unroll
      for (int nt = 0; nt < 4; ++nt) {
        int dk = nt * 16 + l15;
        vf[kt][nt] =
            *(const bf16x8*)&vs[dk * 64 + (((kt * 4 + quad) ^ (l15 & 7)) << 3)];
      }

    // ---- exp2 + packed P store: one b64 per (qt,tt) ----
#pragma unroll
    for (int qt = 0; qt < 2; ++qt) {
      float acc = 0.f;
#pragma unroll
      for (int tt = 0; tt < 4; ++tt) {
        bf16x4 pk;
#pragma unroll
        for (int r = 0; r < 4; ++r) {
          float e = __builtin_exp2f(s[qt][tt][r]);   // Q carries 0.125*log2e
          acc += e;
          pk[r] = (__bf16)e;
        }
        *(bf16x4*)&P[wave][qt * 1024 + pst[tt]] = pk;
      }
      lsum[qt] += acc;
    }

    asm volatile("" ::: "memory");  // pin P stores above the P reads (TBAA)

    // ---- PV: P read back as A-frag via b128; V frags shared ----
    __builtin_amdgcn_s_setprio(1);
#pragma unroll
    for (int qt = 0; qt < 2; ++qt)
#pragma unroll
      for (int kt = 0; kt < 2; ++kt) {
        bf16x8 pf = *(const bf16x8*)&P[wave][qt * 1024 + prd[kt]];
#pragma unroll
        for (int nt = 0; nt < 4; ++nt)
          o[qt][nt] = __builtin_amdgcn_mfma_f32_16x16x32_bf16(
              pf, vf[kt][nt], o[qt][nt], 0, 0, 0);
      }
    __builtin_amdgcn_s_setprio(0);

    __syncthreads();  // drains staging vmcnt; separates buffer reuse
  }

  // lsum finish: all keys of a q-row live in lanes with same l15
#pragma unroll
  for (int qt = 0; qt < 2; ++qt) {
    float v = lsum[qt];
    v += __shfl_xor(v, 16, 64);
    v += __shfl_xor(v, 32, 64);
    lsum[qt] = v;  // every lane: sum for q = l15 (of tile qt)
  }

#pragma unroll
  for (int qt = 0; qt < 2; ++qt) {
    float rinv[4];
#pragma unroll
    for (int r = 0; r < 4; ++r)
      rinv[r] = 1.0f / __shfl(lsum[qt], quad * 4 + r, 64);
#pragma unroll
    for (int nt = 0; nt < 4; ++nt)
#pragma unroll
      for (int r = 0; r < 4; ++r) {
        int qrow = q0 + qt * 16 + quad * 4 + r;
        Out[(size_t)bh * S_ * DK_ + (size_t)qrow * DK_ + nt * 16 + l15] =
            (__bf16)(o[qt][nt][r] * rinv[r]);
      }
  }
}

extern "C" void kernel_launch(void* const* d_in, const int* in_sizes, int n_in,
                              void* d_out, int out_size, void* d_ws, size_t ws_size,
                              hipStream_t stream) {
  const void* q = d_in[0];
  const void* k = d_in[1];
  const void* v = d_in[2];
  const int* mask = (const int*)d_in[3];
  const void* Wq = d_in[4];
  const void* Wk = d_in[5];
  const void* Wv = d_in[6];
  const void* Wo = d_in[7];

  const size_t NE = (size_t)B_ * H_ * S_ * DK_;  // 4,194,304 elems
  __bf16* Qh = (__bf16*)d_ws;                    // ws[0 : 8M)  -> becomes ctx
  __bf16* Kh = Qh + NE;                          // ws[8M : 16M)
  __bf16* Vt = (__bf16*)d_out;                   // scratch; dead before final write

  dim3 g1(16, 4, 3);
  gemmqkv<<<g1, 512, 0, stream>>>(q, k, v, Wq, Wk, Wv, Qh, Kh, Vt,
                                  (const unsigned*)q);
  attn<<<512, 256, 0, stream>>>(Qh, Kh, Vt, mask, Qh);
  dim3 g2(64, 8, 1);
  gemmk<64, 128, 1><<<g2, 256, 0, stream>>>(Qh, Qh, Qh, Wo, Wo, Wo, d_out,
                                            d_out, d_out, (const unsigned*)q);
}

// Round 12
// 251.813 us; speedup vs baseline: 1.0534x; 1.0534x over previous
//
#include <hip/hip_runtime.h>

// MHA: B=2, S=2048, D=1024, H=16, DK=64. I/O bf16 (harness-confirmed R4);
// dual fp32 path retained via runtime inline detect. mask int32.
//
// Pipeline (ws 16 MB; d_out doubles as V scratch) -- 3 dispatches:
//   1) gemmk<128,128,0>: Q/K/V proj (one launch, z selects tensor).
//        z=0: Qh [B,H,S,DK] pre-scaled by 0.125*log2e; z=1: Kh;
//        z=2: Vt [B,H,DK,S] transposed.
//   2) attn (R18 form): flash, 128 q-rows/block, XCD swizzle + setprio.
//   3) gemmk<64,128,1>: out = ctx @ Wo^T -> d_out (512 blocks).
//
// MFMA 16x16x32 bf16 layouts (verified):
//   A: lane holds A[m=lane&15][k=(lane>>4)*8+j]
//   B: lane holds B[k=(lane>>4)*8+j][n=lane&15]
//   C/D: col=lane&15, row=(lane>>4)*4+reg
//
// R4: no u16/bf16 punning (TBAA reorder -> NaN).
// R10 FAILED: ds_read_b64_tr_b16 gather model wrong.
// R11: swapped-MFMA packed-P attn 85.6 -> 75.6 us.
// R12-R17: gemm schedule ladder (dbuf, 2x occupancy, counted-vmcnt,
//   BK=128, tile sweeps) ALL flat-to-worse at 77-90 us.
// R18: attn XCD-swizzle + setprio = big win (~20-30us); gemm XCD-swizzle
//   backfired (A-panel L2 thrash, FETCH 3x).
// R19 (248.9, BEST): gemm natural order + R18 attn. QKV ~80us = 320 TF
//   = exactly the m97-structure's measured value at this scale (m102).
// R20 REGRESSION (265.3): 256^2/BK=32/depth-4 pipeline. Diagnosed:
//   (a) BK=32 4-chunk XOR swizzle = 4-way read conflict (2.36M measured;
//   the XOR must span the full row-period: BK=64's 8 chunks work);
//   (b) grid 192 < 256 CUs; (c) 1 block/CU exposes every stall.
//   8th failed attempt to beat the 2-barrier gemm => structural plateau.
// R21 (this round): REVERT to R19 exactly. This is the accepted final
//   structure unless counters surprise.

typedef __bf16 bf16x8 __attribute__((ext_vector_type(8)));
typedef __bf16 bf16x4 __attribute__((ext_vector_type(4)));
typedef float f32x4 __attribute__((ext_vector_type(4)));

#define B_ 2
#define S_ 2048
#define D_ 1024
#define H_ 16
#define DK_ 64
#define QSCALE 0.18033688011112042f  // 0.125 * log2(e)

// ---------------------------------------------------------------------------
// per-wave inline dtype detect: classify first 256 words of q. bf16 pairs
// put a real exponent at bits [14:7]; f32 words put mantissa there.
// All waves read the same 1KB (L2-broadcast) and agree on the result.
__device__ __forceinline__ bool detect_f32_wave(const unsigned* qw, int lane) {
  int cnt = 0;
#pragma unroll
  for (int i = 0; i < 4; ++i) {
    unsigned w = qw[lane + 64 * i];
    int e = (w >> 7) & 0xFF;
    cnt += (e >= 100 && e <= 140) ? 1 : 0;
  }
#pragma unroll
  for (int off = 32; off > 0; off >>= 1) cnt += __shfl_down(cnt, off, 64);
  return __shfl(cnt, 0, 64) < 128;
}

__device__ __forceinline__ bf16x8 load8cvt(const void* base, size_t eoff,
                                           bool f32) {
  if (!f32) return *(const bf16x8*)((const __bf16*)base + eoff);
  const float* p = (const float*)base + eoff;
  bf16x8 r;
#pragma unroll
  for (int j = 0; j < 8; ++j) r[j] = (__bf16)p[j];
  return r;
}

// async 16B global -> LDS (lds dest = wave-uniform base + lane*16)
__device__ __forceinline__ void async_cp16(const __bf16* g, __bf16* l) {
  __builtin_amdgcn_global_load_lds(
      (const __attribute__((address_space(1))) unsigned int*)g,
      (__attribute__((address_space(3))) unsigned int*)l, 16, 0, 0);
}

// ---------------------------------------------------------------------------
// GEMM (R19 form): C[M,N] = X[M,K] @ W[N,K]^T, TM x TN tile, BK=64,
// single LDS buffer, proven 2-barrier K-step {barrier; stage; barrier;
// compute}. NATURAL block order (round-robin dispatch partitions A
// m-panels across XCD L2s -- measured best).
// LDS [rows][64]; 16B chunks XOR-swizzled (phys j = jl ^ (row&7)) --
// proven zero-conflict BK=64 layout (XOR spans the full 8-chunk row
// period; narrower XORs alias, see R20). Staging: linear LDS dest +
// pre-swizzled global source (rule #21). f32 fallback: reg-staged.
// ---------------------------------------------------------------------------
template <int TM, int TN, int MODE>
__global__ __launch_bounds__(256) void gemmk(
    const void* X0, const void* X1, const void* X2,
    const void* W0, const void* W1, const void* W2,
    void* O0, void* O1, void* O2, const unsigned* __restrict__ qdet) {
  constexpr int Kd = 1024, Nd = 1024;
  constexpr int MI = TM / 32;     // m-frags per wave
  constexpr int NI = TN / 32;     // n-frags per wave
  constexpr int ACH = TM / 32;    // A staging cp16 per wave (1KB each)
  constexpr int BCH = TN / 32;    // B staging cp16 per wave
  const void* X = (blockIdx.z == 0) ? X0 : (blockIdx.z == 1 ? X1 : X2);
  const void* W = (blockIdx.z == 0) ? W0 : (blockIdx.z == 1 ? W1 : W2);
  void* O = (blockIdx.z == 0) ? O0 : (blockIdx.z == 1 ? O1 : O2);

  __shared__ __attribute__((aligned(16))) __bf16 As[TM * 64];
  __shared__ __attribute__((aligned(16))) __bf16 Bs[TN * 64];

  const int m0 = blockIdx.x * TM;
  const int n0 = blockIdx.y * TN;
  const int t = threadIdx.x;
  const int lane = t & 63, wave = t >> 6;
  const int l15 = lane & 15, quad = lane >> 4;
  const int wm = (wave >> 1) * (TM / 2);
  const int wn = (wave & 1) * (TN / 2);

  const bool f32io = detect_f32_wave(qdet, lane);

  const __bf16* gA[ACH];
  int ldsAoff[ACH];
#pragma unroll
  for (int i = 0; i < ACH; ++i) {
    int ci = (wave * ACH + i) * 64 + lane;
    int row = ci >> 3, j = ci & 7;
    int jl = j ^ (row & 7);
    ldsAoff[i] = (wave * ACH + i) * 512;
    if (MODE == 0) {
      gA[i] = (const __bf16*)X + (size_t)(m0 + row) * Kd + jl * 8;
    } else {
      int gm = m0 + row;
      gA[i] = (const __bf16*)X + (size_t)(gm >> 11) * (H_ * S_ * DK_) +
              (size_t)(gm & (S_ - 1)) * DK_ + jl * 8;
    }
  }
  const __bf16* gB[BCH];
  int ldsBoff[BCH];
#pragma unroll
  for (int i = 0; i < BCH; ++i) {
    int ci = (wave * BCH + i) * 64 + lane;
    int row = ci >> 3, j = ci & 7;
    int jl = j ^ (row & 7);
    ldsBoff[i] = (wave * BCH + i) * 512;
    gB[i] = (const __bf16*)W + (size_t)(n0 + row) * Kd + jl * 8;
  }

  f32x4 acc[MI][NI] = {};

  for (int k0 = 0; k0 < Kd; k0 += 64) {
    __syncthreads();
    if (!f32io) {
      if (MODE == 0) {
#pragma unroll
        for (int i = 0; i < ACH; ++i) async_cp16(gA[i] + k0, &As[ldsAoff[i]]);
      } else {
        const size_t koff = (size_t)(k0 >> 6) * (S_ * DK_);
#pragma unroll
        for (int i = 0; i < ACH; ++i) async_cp16(gA[i] + koff, &As[ldsAoff[i]]);
      }
#pragma unroll
      for (int i = 0; i < BCH; ++i) async_cp16(gB[i] + k0, &Bs[ldsBoff[i]]);
    } else {
#pragma unroll
      for (int i = 0; i < TM / 32; ++i) {
        int ci = t + 256 * i;
        int row = ci >> 3, j = ci & 7;
        int jl = j ^ (row & 7);
        bf16x8 xv;
        if (MODE == 0) {
          xv = load8cvt(X, (size_t)(m0 + row) * Kd + k0 + jl * 8, true);
        } else {
          int gm = m0 + row, gk = k0 + jl * 8;
          xv = *(const bf16x8*)((const __bf16*)X +
                ((((size_t)(gm >> 11) * H_ + (gk >> 6)) * S_) +
                 (gm & (S_ - 1))) * DK_ + (gk & (DK_ - 1)));
        }
        *(bf16x8*)&As[row * 64 + j * 8] = xv;
      }
#pragma unroll
      for (int i = 0; i < TN / 32; ++i) {
        int ci = t + 256 * i;
        int row = ci >> 3, j = ci & 7;
        int jl = j ^ (row & 7);
        bf16x8 wv = load8cvt(W, (size_t)(n0 + row) * Kd + k0 + jl * 8, true);
        *(bf16x8*)&Bs[row * 64 + j * 8] = wv;
      }
    }
    __syncthreads();

#pragma unroll
    for (int h = 0; h < 2; ++h) {
      bf16x8 af[MI], bfr[NI];
#pragma unroll
      for (int mi = 0; mi < MI; ++mi) {
        int row = wm + mi * 16 + l15;
        af[mi] = *(const bf16x8*)&As[row * 64 +
                                     (((h * 4 + quad) ^ (row & 7)) << 3)];
      }
#pragma unroll
      for (int ni = 0; ni < NI; ++ni) {
        int row = wn + ni * 16 + l15;
        bfr[ni] = *(const bf16x8*)&Bs[row * 64 +
                                      (((h * 4 + quad) ^ (row & 7)) << 3)];
      }
#pragma unroll
      for (int mi = 0; mi < MI; ++mi)
#pragma unroll
        for (int ni = 0; ni < NI; ++ni)
          acc[mi][ni] = __builtin_amdgcn_mfma_f32_16x16x32_bf16(
              af[mi], bfr[ni], acc[mi][ni], 0, 0, 0);
    }
  }

  const float oscale = (MODE == 0 && blockIdx.z == 0) ? QSCALE : 1.0f;
#pragma unroll
  for (int mi = 0; mi < MI; ++mi) {
#pragma unroll
    for (int ni = 0; ni < NI; ++ni) {
      int mbase = m0 + wm + mi * 16 + quad * 4;
      int n = n0 + wn + ni * 16 + l15;
      if (MODE == 0 && blockIdx.z == 2) {
        int b = mbase >> 11, sb = mbase & (S_ - 1);
        int h = n >> 6, dk = n & (DK_ - 1);
        bf16x4 pk;
#pragma unroll
        for (int r = 0; r < 4; ++r) pk[r] = (__bf16)acc[mi][ni][r];
        *(bf16x4*)&((__bf16*)O)[((size_t)(b * H_ + h) * DK_ + dk) * S_ + sb] = pk;
      } else {
#pragma unroll
        for (int r = 0; r < 4; ++r) {
          int m = mbase + r;
          float val = acc[mi][ni][r] * oscale;
          if (MODE == 0) {
            int b = m >> 11, s = m & (S_ - 1);
            int h = n >> 6, dk = n & (DK_ - 1);
            ((__bf16*)O)[((size_t)(b * H_ + h) * S_ + s) * DK_ + dk] = (__bf16)val;
          } else {
            size_t idx = (size_t)m * Nd + n;
            if (f32io) ((float*)O)[idx] = val;
            else       ((__bf16*)O)[idx] = (__bf16)val;
          }
        }
      }
    }
  }
}

// ---------------------------------------------------------------------------
// Flash attention (R18 form, byte-identical): 128 q-rows/block (32/wave
// as 2 q-tiles), 64 keys/iter, grid 512. XCD-bijective swizzle gives each
// XCD 64 consecutive chunks = 4 complete bh-groups -> K/V L2-local.
// Swapped score MFMA: s = mfma(Kfrag, Qfrag, bias) -> lane holds
// s[key=quad*4+r][q=l15]. P per wave per q-tile: [16 q][64 key] rows of
// 128B, 16B chunks XOR-swizzled by (l15&7). Store: one ds_write_b64 per
// (qt,tt); read: one ds_read_b128 per (qt,kt) -> PV A-frag directly.
// K/V frags read once, shared by both q-tiles. T5 setprio around both
// MFMA clusters. Wave-private P: in-order LDS, no barriers; asm fence
// pins store phase above reads.
// ---------------------------------------------------------------------------
__global__ __launch_bounds__(256, 2) void attn(
    const __bf16* Qh, const __bf16* __restrict__ Kh,
    const __bf16* __restrict__ Vt, const int* __restrict__ mask,
    __bf16* Out) {
  __shared__ __attribute__((aligned(16))) __bf16 Ks[2][4096];
  __shared__ __attribute__((aligned(16))) __bf16 Vs[2][4096];
  __shared__ __attribute__((aligned(16))) __bf16 P[4][2048];  // wave: 2 x [16][64]

  const int t = threadIdx.x;
  const int lane = t & 63, wave = t >> 6;
  const int l15 = lane & 15, quad = lane >> 4;
  // XCD-bijective remap (512 = 8 x 64)
  const int L = blockIdx.x;
  const int c = (L & 7) * 64 + (L >> 3);
  const int qb = c & 15;            // 16 q-blocks of 128
  const int bh = c >> 4;            // b*H + h
  const int b = bh >> 4;
  const int q0 = qb * 128 + wave * 32;

  const __bf16* Q = Qh + (size_t)bh * S_ * DK_;
  const __bf16* K = Kh + (size_t)bh * S_ * DK_;
  const __bf16* V = Vt + (size_t)bh * DK_ * S_;   // [dk][s]
  const int* mk = mask + b * S_;

  bf16x8 qf[2][2];
#pragma unroll
  for (int qt = 0; qt < 2; ++qt) {
    qf[qt][0] = *(const bf16x8*)&Q[(size_t)(q0 + qt * 16 + l15) * DK_ + quad * 8];
    qf[qt][1] = *(const bf16x8*)&Q[(size_t)(q0 + qt * 16 + l15) * DK_ + 32 + quad * 8];
  }

  f32x4 o[2][4] = {};
  float lsum[2] = {0.f, 0.f};

  // loop-invariant P element offsets (within P[wave], before qt*1024)
  int pst[4], prd[2];
#pragma unroll
  for (int tt = 0; tt < 4; ++tt)
    pst[tt] = l15 * 64 + (((tt * 2 + (quad >> 1)) ^ (l15 & 7)) << 3) +
              (quad & 1) * 4;
#pragma unroll
  for (int kt = 0; kt < 2; ++kt)
    prd[kt] = l15 * 64 + (((kt * 4 + quad) ^ (l15 & 7)) << 3);

  // prologue: stage tile 0 into buf 0
#pragma unroll
  for (int i = 0; i < 2; ++i) {
    int l = wave * 128 + i * 64 + lane;
    int row = l >> 3, jg = (l & 7) ^ (row & 7);
    async_cp16(K + (size_t)row * DK_ + jg * 8, &Ks[0][(size_t)(l - lane) * 8]);
    async_cp16(V + (size_t)row * S_ + jg * 8, &Vs[0][(size_t)(l - lane) * 8]);
  }
  __syncthreads();

  for (int kb = 0; kb < S_; kb += 64) {
    const int cur = (kb >> 6) & 1;
    if (kb + 64 < S_) {
#pragma unroll
      for (int i = 0; i < 2; ++i) {
        int l = wave * 128 + i * 64 + lane;
        int row = l >> 3, jg = (l & 7) ^ (row & 7);
        async_cp16(K + (size_t)(kb + 64 + row) * DK_ + jg * 8,
                   &Ks[cur ^ 1][(size_t)(l - lane) * 8]);
        async_cp16(V + (size_t)row * S_ + (kb + 64) + jg * 8,
                   &Vs[cur ^ 1][(size_t)(l - lane) * 8]);
      }
    }

    // ---- scores (SWAPPED): s[key=quad*4+r][q=l15]; K frags shared ----
    const __bf16* ks = &Ks[cur][0];
    f32x4 s[2][4];
    __builtin_amdgcn_s_setprio(1);
#pragma unroll
    for (int tt = 0; tt < 4; ++tt) {
      int row = tt * 16 + l15;
      bf16x8 kf0 = *(const bf16x8*)&ks[row * 64 + ((quad ^ (l15 & 7)) << 3)];
      bf16x8 kf1 = *(const bf16x8*)&ks[row * 64 + (((4 + quad) ^ (l15 & 7)) << 3)];
      // per-key mask bias: keys tt*16 + quad*4 .. +3
      int4 m4 = *(const int4*)&mk[kb + tt * 16 + quad * 4];
      f32x4 z;
      z[0] = m4.x ? 0.f : -1e9f;
      z[1] = m4.y ? 0.f : -1e9f;
      z[2] = m4.z ? 0.f : -1e9f;
      z[3] = m4.w ? 0.f : -1e9f;
      f32x4 z0 = __builtin_amdgcn_mfma_f32_16x16x32_bf16(kf0, qf[0][0], z, 0, 0, 0);
      s[0][tt] = __builtin_amdgcn_mfma_f32_16x16x32_bf16(kf1, qf[0][1], z0, 0, 0, 0);
      f32x4 z1 = __builtin_amdgcn_mfma_f32_16x16x32_bf16(kf0, qf[1][0], z, 0, 0, 0);
      s[1][tt] = __builtin_amdgcn_mfma_f32_16x16x32_bf16(kf1, qf[1][1], z1, 0, 0, 0);
    }
    __builtin_amdgcn_s_setprio(0);

    // ---- V fragments (issue while exp phase runs; shared by q-tiles) ----
    const __bf16* vs = &Vs[cur][0];
    bf16x8 vf[2][4];
#pragma unroll
    for (int kt = 0; kt < 2; ++kt)
#pragma unroll
      for (int nt = 0; nt < 4; ++nt) {
        int dk = nt * 16 + l15;
        vf[kt][nt] =
            *(const bf16x8*)&vs[dk * 64 + (((kt * 4 + quad) ^ (l15 & 7)) << 3)];
      }

    // ---- exp2 + packed P store: one b64 per (qt,tt) ----
#pragma unroll
    for (int qt = 0; qt < 2; ++qt) {
      float acc = 0.f;
#pragma unroll
      for (int tt = 0; tt < 4; ++tt) {
        bf16x4 pk;
#pragma unroll
        for (int r = 0; r < 4; ++r) {
          float e = __builtin_exp2f(s[qt][tt][r]);   // Q carries 0.125*log2e
          acc += e;
          pk[r] = (__bf16)e;
        }
        *(bf16x4*)&P[wave][qt * 1024 + pst[tt]] = pk;
      }
      lsum[qt] += acc;
    }

    asm volatile("" ::: "memory");  // pin P stores above the P reads (TBAA)

    // ---- PV: P read back as A-frag via b128; V frags shared ----
    __builtin_amdgcn_s_setprio(1);
#pragma unroll
    for (int qt = 0; qt < 2; ++qt)
#pragma unroll
      for (int kt = 0; kt < 2; ++kt) {
        bf16x8 pf = *(const bf16x8*)&P[wave][qt * 1024 + prd[kt]];
#pragma unroll
        for (int nt = 0; nt < 4; ++nt)
          o[qt][nt] = __builtin_amdgcn_mfma_f32_16x16x32_bf16(
              pf, vf[kt][nt], o[qt][nt], 0, 0, 0);
      }
    __builtin_amdgcn_s_setprio(0);

    __syncthreads();  // drains staging vmcnt; separates buffer reuse
  }

  // lsum finish: all keys of a q-row live in lanes with same l15
#pragma unroll
  for (int qt = 0; qt < 2; ++qt) {
    float v = lsum[qt];
    v += __shfl_xor(v, 16, 64);
    v += __shfl_xor(v, 32, 64);
    lsum[qt] = v;  // every lane: sum for q = l15 (of tile qt)
  }

#pragma unroll
  for (int qt = 0; qt < 2; ++qt) {
    float rinv[4];
#pragma unroll
    for (int r = 0; r < 4; ++r)
      rinv[r] = 1.0f / __shfl(lsum[qt], quad * 4 + r, 64);
#pragma unroll
    for (int nt = 0; nt < 4; ++nt)
#pragma unroll
      for (int r = 0; r < 4; ++r) {
        int qrow = q0 + qt * 16 + quad * 4 + r;
        Out[(size_t)bh * S_ * DK_ + (size_t)qrow * DK_ + nt * 16 + l15] =
            (__bf16)(o[qt][nt][r] * rinv[r]);
      }
  }
}

extern "C" void kernel_launch(void* const* d_in, const int* in_sizes, int n_in,
                              void* d_out, int out_size, void* d_ws, size_t ws_size,
                              hipStream_t stream) {
  const void* q = d_in[0];
  const void* k = d_in[1];
  const void* v = d_in[2];
  const int* mask = (const int*)d_in[3];
  const void* Wq = d_in[4];
  const void* Wk = d_in[5];
  const void* Wv = d_in[6];
  const void* Wo = d_in[7];

  const size_t NE = (size_t)B_ * H_ * S_ * DK_;  // 4,194,304 elems
  __bf16* Qh = (__bf16*)d_ws;                    // ws[0 : 8M)  -> becomes ctx
  __bf16* Kh = Qh + NE;                          // ws[8M : 16M)
  __bf16* Vt = (__bf16*)d_out;                   // scratch; dead before final write

  dim3 g1(32, 8, 3);
  gemmk<128, 128, 0><<<g1, 256, 0, stream>>>(q, k, v, Wq, Wk, Wv, Qh, Kh, Vt,
                                             (const unsigned*)q);
  attn<<<512, 256, 0, stream>>>(Qh, Kh, Vt, mask, Qh);
  dim3 g2(64, 8, 1);
  gemmk<64, 128, 1><<<g2, 256, 0, stream>>>(Qh, Qh, Qh, Wo, Wo, Wo, d_out,
                                            d_out, d_out, (const unsigned*)q);
}